// Round 11
// baseline (672.375 us; speedup 1.0000x reference)
//
#include <hip/hip_runtime.h>
#include <math.h>
#include <float.h>

// EMAVectorQuantizer eval path.  (R11 = byte-identical resubmission of R10's kernel:
// R10's bench died to a container-acquisition infra failure with no kernel verdict.)
//   z: [8, 64, 64, 64] fp32  (B, C=d=64, H, W);  weight: [4096, 64] fp32
//   N = 32768 rows, K = 4096 codes.
//
// d_out (flat fp32): z_q[2097152] | loss | perplexity | encodings[32768*4096] | indices[32768]
#define ZQ_OFF   0
#define LOSS_OFF 2097152
#define PERP_OFF 2097153
#define ENC_OFF  2097154
#define IDX_OFF  136314882ULL
#define BETA     0.25f

// ws layout: [0..4) loss fp32 acc | [4..8) ticket int | [16..16+16384) hist int[4096]
//            [16400 .. +16384) wnorm fp32[4096] | [32800 .. +1572864) w3 bf16 limbs (k-blocked)

typedef __attribute__((ext_vector_type(8))) short short8;   // 8 bf16 = 4 VGPRs
typedef __attribute__((ext_vector_type(4))) float f32x4;
typedef __attribute__((ext_vector_type(2))) float f32x2;

#define MFMA16(a, b, c) __builtin_amdgcn_mfma_f32_16x16x32_bf16(a, b, c, 0, 0, 0)

// round-to-nearest-even fp32 -> bf16
__device__ __forceinline__ float bf16_rn(float v, unsigned short* h) {
    unsigned u = __float_as_uint(v);
    unsigned r = (u + 0x7fffu + ((u >> 16) & 1u)) & 0xffff0000u;
    *h = (unsigned short)(r >> 16);
    return __uint_as_float(r);
}
// v = hi + mid + lo to ~2^-27 relative (split residuals exact in fp32)
__device__ __forceinline__ void split3(float v, unsigned short* h, unsigned short* m, unsigned short* l) {
    float hf = bf16_rn(v, h);
    float r1 = v - hf;            // exact
    float mf = bf16_rn(r1, m);
    float r2 = r1 - mf;           // exact
    bf16_rn(r2, l);
}

__global__ void vq_wnorm(const float* __restrict__ w, float* __restrict__ wnorm) {
    int c = blockIdx.x * 256 + threadIdx.x;
    const float4* w4 = (const float4*)(w + ((size_t)c << 6));
    float s = 0.f;
    #pragma unroll
    for (int k = 0; k < 16; ++k) { float4 v = w4[k]; s += v.x*v.x + v.y*v.y + v.z*v.z + v.w*v.w; }
    wnorm[c] = s;
}

// w3 layout (B-fragment-native, HW-verified R7-R9): for half-chunk hb = code>>4
// (16 codes), limb p (0=hi,1=mid,2=lo), k-half s, k-quarter lkq, code-in-half cl:
//   byte = (((hb*3 + p)*2 + s)*4 + lkq)*256 + cl*16   (6144 B per hb-block)
// holding the 8 bf16 of k = s*32 + lkq*8 .. +7. Lane l = lkq*16+lcol reads its MFMA
// B-fragment at block_base + l*16 — PURE LANE-LINEAR: zero LDS bank conflicts, and
// global_load_lds stages it as a straight linear copy.
__global__ void vq_prep(const float* __restrict__ w, unsigned short* __restrict__ w3) {
    int u = blockIdx.x * 256 + threadIdx.x;      // 512 blocks -> 131072 threads
    int c = u >> 5, slot = u & 31;               // 32 threads/code, 24 active
    if (slot >= 24) return;
    int p = slot >> 3, g = slot & 7;             // g = k-group: s = g>>2, lkq = g&3
    float4 v0 = *(const float4*)(w + ((size_t)c << 6) + g * 8);
    float4 v1 = *(const float4*)(w + ((size_t)c << 6) + g * 8 + 4);
    float vv[8] = {v0.x, v0.y, v0.z, v0.w, v1.x, v1.y, v1.z, v1.w};
    short8 o;
    #pragma unroll
    for (int e = 0; e < 8; ++e) {
        unsigned short h, m, l;
        split3(vv[e], &h, &m, &l);
        o[e] = (short)((p == 0) ? h : (p == 1) ? m : l);
    }
    size_t db = (size_t)((((c >> 4) * 3 + p) * 2 + (g >> 2)) * 4 + (g & 3)) * 256
              + (size_t)(c & 15) * 16;
    *(short8*)((char*)w3 + db) = o;
}

// Block: 256 threads = 4 waves, 64 rows. Wave wv: rh=wv&1 (rows rh*32..+31),
// chalf=wv>>1 (codes chalf*16..+15 of each 32-code chunk, 128 chunks).
// DEPTH-3 PREFETCH RING: each wave owns 4 private 6144-B LDS slices; iteration k
// computes slot k&3 while DMAs for k+1..k+3 are in flight. The vmcnt wait at iter k
// targets a DMA issued at k-3 (~3 iters of compute cover) — the depth-1 wait that
// every R3-R9 variant shared (and that kept the loop at ~4000 cyc/iter) is gone.
// Barrier-free loop (private slices, R6-proven); lane-linear LDS (R8/R9-proven).
// Per iter FIFO: [6 DMA][4 NT st]; younger-than-DMA(k) = 4+6+4+6+4+6+4 = 34.
// Ring-slot overwrite hazard check: DMA issued at iter k overwrites slot (k-1)&3,
// whose ds_reads were lgkm-consumed into VGPRs before this DMA issues (program
// order); slices are wave-private -> no cross-wave hazard.
__global__ __launch_bounds__(256, 1) void vq_main(
    const float* __restrict__ z, const float* __restrict__ w,
    const float* __restrict__ wnorm, const unsigned short* __restrict__ w3,
    float* __restrict__ out,
    float* __restrict__ loss_ws, int* __restrict__ ticket, int* __restrict__ hist)
{
    __shared__ __align__(16) char ring[4 * 4 * 6144];   // [wave][slot], 98304 B, private
    __shared__ float zS[64][64];                        // persistent z tile (z_q tail)
    __shared__ float snorm[4096];                       // wnorm in LDS (lgkm, not vmcnt)
    __shared__ int s_widx[64];
    __shared__ int s_flag;

    const int tx    = threadIdx.x;
    const int lane  = tx & 63;
    const int wv    = tx >> 6;
    const int rh    = wv & 1;            // row half: rows rh*32 .. +31
    const int chalf = wv >> 1;           // code half within each 32-code chunk
    const int lcol  = lane & 15;         // B col / A row within 16-group
    const int lkq   = lane >> 4;         // k-quarter (8 k's each)
    const int base  = blockIdx.x * 64;   // global rows [base, base+64)
    const int bb    = base >> 12;        // b
    const int hh    = (base & 4095) >> 6;// h   (w coordinate = row-in-block)

    const char* wsrc = (const char*)w3 + (size_t)lane * 16;
    char* ringw = ring + wv * 24576;

    // ---- issue depth-3 prefetch of chunks 0..2 (drained by the staging sync) ----
    #pragma unroll
    for (int p = 0; p < 3; ++p) {
        const char* s0 = wsrc + (size_t)(p * 2 + chalf) * 6144;
        char* d0 = ringw + p * 6144;
        #pragma unroll
        for (int i = 0; i < 6; ++i)
            __builtin_amdgcn_global_load_lds(
                (const __attribute__((address_space(1))) void*)(s0 + i * 1024),
                (__attribute__((address_space(3))) void*)(d0 + i * 1024), 16, 0, 0);
    }

    // ---- stage z[bb][:][hh][:] -> zS; wnorm -> snorm ----
    #pragma unroll
    for (int j = 0; j < 4; ++j) {
        int f4 = j * 256 + tx;           // 0..1023
        int d  = f4 >> 4, w4i = f4 & 15;
        float4 v = *(const float4*)(z + (((size_t)bb * 64 + d) * 64 + hh) * 64 + w4i * 4);
        *(float4*)&zS[d][w4i * 4] = v;
    }
    #pragma unroll
    for (int j = 0; j < 4; ++j) {
        int c4 = (j * 256 + tx) * 4;
        *(float4*)&snorm[c4] = *(const float4*)(wnorm + c4);
    }
    __syncthreads();                     // drains vmcnt(0): z, wnorm AND chunks 0..2

    // ---- A fragments (z limbs), 2 tiles u: rows rh*32 + u*16 + lcol ----
    short8 aH[2][2], aM[2][2], aL[2][2];             // [u][s], k = s*32 + lkq*8 + j
    #pragma unroll
    for (int u = 0; u < 2; ++u)
        #pragma unroll
        for (int s = 0; s < 2; ++s)
            #pragma unroll
            for (int j = 0; j < 8; ++j) {
                float v = zS[s * 32 + lkq * 8 + j][rh * 32 + u * 16 + lcol];
                unsigned short h, m, l;
                split3(v, &h, &m, &l);
                aH[u][s][j] = (short)h; aM[u][s][j] = (short)m; aL[u][s][j] = (short)l;
            }

    float best[2][4]; int bidx[2][4];
    #pragma unroll
    for (int u = 0; u < 2; ++u)
        #pragma unroll
        for (int r = 0; r < 4; ++r) { best[u][r] = FLT_MAX; bidx[u][r] = 0; }

    float* enc = out + ENC_OFF;          // 8-B aligned region
    const f32x2 zero2 = {0.f, 0.f};

    // Per iter (NO barriers): [6 DMA chunk k+3][SB][4 NT zero st][SB][vmcnt(34)][compute].
    // k=0..2: needed chunks already retired pre-loop; queue <=30 so vmcnt(34) is free.
    // k>=3 steady: retires exactly DMA(k) (issued at k-3), leaves k+1..k+3 + stores in flight.
    #pragma unroll 1
    for (int k = 0; k < 128; ++k) {
        const int slot = k & 3;
        // prefetch chunk k+3 (k>=125: dead reload of chunks 0..2, slots already consumed)
        {
            const char* s0 = wsrc + (size_t)((((k + 3) & 127) * 2 + chalf)) * 6144;
            char* d0 = ringw + ((k + 3) & 3) * 6144;
            #pragma unroll
            for (int i = 0; i < 6; ++i)
                __builtin_amdgcn_global_load_lds(
                    (const __attribute__((address_space(1))) void*)(s0 + i * 1024),
                    (__attribute__((address_space(3))) void*)(d0 + i * 1024), 16, 0, 0);
        }
        __builtin_amdgcn_sched_barrier(0);   // pin FIFO order: DMA before stores
        // zero-fill half enc row (base + k/2, half k&1), nontemporal; +7 slot rotation
        // keeps each 512-B request 64-B aligned (enc base is +8 mod 64)
        {
            f32x2* rowp = (f32x2*)(enc + ((size_t)(base + (k >> 1)) << 12));
            #pragma unroll
            for (int j = 0; j < 4; ++j) {
                int slt = (k & 1) * 1024 + ((j * 256 + tx + 7) & 1023);
                __builtin_nontemporal_store(zero2, rowp + slt);
            }
        }
        __builtin_amdgcn_sched_barrier(0);
        asm volatile("s_waitcnt vmcnt(34)" ::: "memory");   // chunk k resident in slot
        __builtin_amdgcn_sched_barrier(0);

        // ---- compute: dist = ||w||^2 - 2*z.w (row norm constant; argmin unaffected)
        // limb products: hh + (hm+mh) + (mm+hl+lh); dropped ~2^-27 rel.
        // B-reads lane-linear (base + lane*16): zero bank conflicts.
        {
            const int code0 = k * 32 + chalf * 16;
            const char* bufc = ringw + slot * 6144 + (size_t)lane * 16;
            short8 bH0 = *(const short8*)(bufc);
            short8 bH1 = *(const short8*)(bufc + 1024);
            short8 bM0 = *(const short8*)(bufc + 2048);
            short8 bM1 = *(const short8*)(bufc + 3072);
            short8 bL0 = *(const short8*)(bufc + 4096);
            short8 bL1 = *(const short8*)(bufc + 5120);
            const float wnv = snorm[code0 + lcol];
            #pragma unroll
            for (int u = 0; u < 2; ++u) {
                f32x4 c0 = {0.f,0.f,0.f,0.f}, c1 = {0.f,0.f,0.f,0.f}, c2 = {0.f,0.f,0.f,0.f};
                c0 = MFMA16(aH[u][0], bH0, c0); c0 = MFMA16(aH[u][1], bH1, c0);
                c1 = MFMA16(aH[u][0], bM0, c1); c1 = MFMA16(aH[u][1], bM1, c1);
                c1 = MFMA16(aM[u][0], bH0, c1); c1 = MFMA16(aM[u][1], bH1, c1);
                c2 = MFMA16(aM[u][0], bM0, c2); c2 = MFMA16(aM[u][1], bM1, c2);
                c2 = MFMA16(aH[u][0], bL0, c2); c2 = MFMA16(aH[u][1], bL1, c2);
                c2 = MFMA16(aL[u][0], bH0, c2); c2 = MFMA16(aL[u][1], bH1, c2);
                #pragma unroll
                for (int r = 0; r < 4; ++r) {
                    float sdot = (c0[r] + c1[r]) + c2[r];
                    float dd = fmaf(-2.f, sdot, wnv);
                    if (dd < best[u][r]) { best[u][r] = dd; bidx[u][r] = code0 + lcol; }
                }
            }
        }
    }

    __syncthreads();                     // vmcnt(0): dead DMAs + ALL zero-fill stores drained

    // ---- intra-wave argmin butterfly over the 16 code-columns (tie -> lower index) ----
    #pragma unroll
    for (int u = 0; u < 2; ++u)
        #pragma unroll
        for (int mm = 1; mm < 16; mm <<= 1)
            #pragma unroll
            for (int r = 0; r < 4; ++r) {
                float ob = __shfl_xor(best[u][r], mm, 64);
                int   oi = __shfl_xor(bidx[u][r], mm, 64);
                if (ob < best[u][r] || (ob == best[u][r] && oi < bidx[u][r])) {
                    best[u][r] = ob; bidx[u][r] = oi;
                }
            }

    // ---- cross-wave merge of the two code-halves (waves wv and wv^2 share rows) ----
    float2* s_red = (float2*)snorm;      // [64][2]; snorm loop reads are done
    if (lcol == 0) {
        #pragma unroll
        for (int u = 0; u < 2; ++u)
            #pragma unroll
            for (int r = 0; r < 4; ++r) {
                int row = rh * 32 + u * 16 + lkq * 4 + r;   // m89-verified C layout
                s_red[row * 2 + chalf] = make_float2(best[u][r], __int_as_float(bidx[u][r]));
            }
    }
    __syncthreads();

    if (tx < 64) {
        float2 a = s_red[tx * 2], b2 = s_red[tx * 2 + 1];
        int ai = __float_as_int(a.y), bi2 = __float_as_int(b2.y);
        int bi;
        if (a.x < b2.x || (a.x == b2.x && ai < bi2)) bi = ai; else bi = bi2;
        s_widx[tx] = bi;
        __builtin_nontemporal_store((float)bi, out + IDX_OFF + (size_t)(base + tx));
        atomicAdd(&hist[bi], 1);
        enc[((size_t)(base + tx) << 12) + bi] = 1.0f;   // zero-fill drained above
    }
    __syncthreads();

    // ---- z_q (STE rounding) + commitment loss partial; z from persistent zS ----
    {
        const int row = tx & 63;
        const int dg  = tx >> 6;           // 4 waves x 16 d each
        const int wi  = s_widx[row];
        const float* qrow = w + ((size_t)wi << 6);
        float lsum = 0.f;
        #pragma unroll
        for (int dd = 0; dd < 16; ++dd) {
            int d = dg * 16 + dd;
            float qv = qrow[d];
            float zv = zS[d][row];
            float diff = qv - zv;
            lsum += diff * diff;
            __builtin_nontemporal_store(zv + (qv - zv),
                out + ZQ_OFF + (((size_t)bb * 64 + d) * 64 + hh) * 64 + row);
        }
        #pragma unroll
        for (int off = 32; off > 0; off >>= 1) lsum += __shfl_down(lsum, off, 64);
        if ((tx & 63) == 0) atomicAdd(loss_ws, lsum);
    }

    // ---- fused finalize: last block computes loss scalar + perplexity ----
    __syncthreads();
    if (tx == 0) {
        __threadfence();
        int old = atomicAdd(ticket, 1);
        s_flag = (old == 511) ? 1 : 0;
    }
    __syncthreads();
    if (s_flag) {
        __threadfence();
        float s = 0.f;
        #pragma unroll
        for (int j = 0; j < 16; ++j) {
            int c = tx + j * 256;
            int cnt = atomicAdd(&hist[c], 0);          // device-coherent read
            float p = (float)cnt * (1.f / 32768.f);
            s += p * logf(p + 1e-10f);
        }
        float* fr = snorm;
        fr[tx] = s;
        __syncthreads();
        for (int off = 128; off > 0; off >>= 1) {
            if (tx < off) fr[tx] += fr[tx + off];
            __syncthreads();
        }
        if (tx == 0) {
            out[LOSS_OFF] = BETA * atomicAdd(loss_ws, 0.f) / 2097152.f;
            out[PERP_OFF] = expf(-fr[0]);
        }
    }
}

extern "C" void kernel_launch(void* const* d_in, const int* in_sizes, int n_in,
                              void* d_out, int out_size, void* d_ws, size_t ws_size,
                              hipStream_t stream)
{
    const float* z = (const float*)d_in[0];
    const float* w = (const float*)d_in[1];
    float* out     = (float*)d_out;
    float* loss_ws = (float*)d_ws;
    int*   ticket  = (int*)((char*)d_ws + 4);
    int*   hist    = (int*)((char*)d_ws + 16);
    float* wnorm   = (float*)((char*)d_ws + 16400);
    unsigned short* w3 = (unsigned short*)((char*)d_ws + 32800);   // 1.5 MB k-blocked limb table
    (void)ws_size; (void)in_sizes; (void)n_in; (void)out_size;

    hipMemsetAsync(d_ws, 0, 16 + 4096 * sizeof(int), stream);
    vq_wnorm<<<16, 256, 0, stream>>>(w, wnorm);
    vq_prep<<<512, 256, 0, stream>>>(w, w3);
    vq_main<<<512, 256, 0, stream>>>(z, w, wnorm, w3, out, loss_ws, ticket, hist);
}

// Round 12
// 600.870 us; speedup vs baseline: 1.1190x; 1.1190x over previous
//
#include <hip/hip_runtime.h>
#include <math.h>
#include <float.h>

// EMAVectorQuantizer eval path.  (FINAL: byte-identical restore of the round-4 kernel,
// the session's empirical best — 601.1 µs total, absmax 0. Subsequent experiments
// R5-R11 falsified store-coupling, barrier-lockstep, bank-conflict, occupancy,
// arithmetic-intensity, register-staging, and prefetch-depth theories; none beat this.)
//   z: [8, 64, 64, 64] fp32  (B, C=d=64, H, W);  weight: [4096, 64] fp32
//   N = 32768 rows, K = 4096 codes.
//
// d_out (flat fp32): z_q[2097152] | loss | perplexity | encodings[32768*4096] | indices[32768]
#define ZQ_OFF   0
#define LOSS_OFF 2097152
#define PERP_OFF 2097153
#define ENC_OFF  2097154
#define IDX_OFF  136314882ULL
#define BETA     0.25f

// ws layout: [0..4) loss fp32 acc | [4..8) ticket int | [16..16+16384) hist int[4096]
//            [16400 .. +16384) wnorm fp32[4096] | [32800 .. +1572864) w3 bf16 limbs, swizzled

typedef __attribute__((ext_vector_type(8))) short short8;   // 8 bf16 = 4 VGPRs
typedef __attribute__((ext_vector_type(4))) float f32x4;
typedef __attribute__((ext_vector_type(2))) float f32x2;

#define MFMA16(a, b, c) __builtin_amdgcn_mfma_f32_16x16x32_bf16(a, b, c, 0, 0, 0)

// round-to-nearest-even fp32 -> bf16
__device__ __forceinline__ float bf16_rn(float v, unsigned short* h) {
    unsigned u = __float_as_uint(v);
    unsigned r = (u + 0x7fffu + ((u >> 16) & 1u)) & 0xffff0000u;
    *h = (unsigned short)(r >> 16);
    return __uint_as_float(r);
}
// v = hi + mid + lo to ~2^-27 relative (split residuals exact in fp32)
__device__ __forceinline__ void split3(float v, unsigned short* h, unsigned short* m, unsigned short* l) {
    float hf = bf16_rn(v, h);
    float r1 = v - hf;            // exact
    float mf = bf16_rn(r1, m);
    float r2 = r1 - mf;           // exact
    bf16_rn(r2, l);
}

__global__ void vq_wnorm(const float* __restrict__ w, float* __restrict__ wnorm) {
    int c = blockIdx.x * 256 + threadIdx.x;
    const float4* w4 = (const float4*)(w + ((size_t)c << 6));
    float s = 0.f;
    #pragma unroll
    for (int k = 0; k < 16; ++k) { float4 v = w4[k]; s += v.x*v.x + v.y*v.y + v.z*v.z + v.w*v.w; }
    wnorm[c] = s;
}

// w3 layout: per code c a 384-B row: limb p in [p*128, p*128+128), 16-B slot g holds
// shorts d = g*8..g*8+7, stored at byte ((p*128 + g*16) ^ ((c&7)<<4)) within the row.
// Swizzle baked into GLOBAL memory so vq_main's global_load_lds is a pure linear copy
// (swizzle both-sides-or-neither) and LDS b128 reads are conflict-free.
__global__ void vq_prep(const float* __restrict__ w, unsigned short* __restrict__ w3) {
    int u = blockIdx.x * 256 + threadIdx.x;      // 512 blocks -> 131072 threads
    int c = u >> 5, slot = u & 31;               // 32 threads/code, 24 active
    if (slot >= 24) return;
    int p = slot >> 3, g = slot & 7;
    float4 v0 = *(const float4*)(w + ((size_t)c << 6) + g * 8);
    float4 v1 = *(const float4*)(w + ((size_t)c << 6) + g * 8 + 4);
    float vv[8] = {v0.x, v0.y, v0.z, v0.w, v1.x, v1.y, v1.z, v1.w};
    short8 o;
    #pragma unroll
    for (int e = 0; e < 8; ++e) {
        unsigned short h, m, l;
        split3(vv[e], &h, &m, &l);
        o[e] = (short)((p == 0) ? h : (p == 1) ? m : l);
    }
    char* dst = (char*)w3 + (size_t)c * 384 + (((unsigned)slot * 16) ^ (((unsigned)c & 7) << 4));
    *(short8*)dst = o;
}

// Block: 256 threads = 4 waves. Wave wv: rh=wv&1 (rows rh*32..+31, two 16-row A-tiles),
// chalf=wv>>1 (codes chalf*32..+31 of each 64-code chunk). Halves redundant LDS B-reads
// vs all-waves-read-all-codes. Chunks double-buffered via global_load_lds; raw s_barrier
// + counted s_waitcnt vmcnt(14) (6 DMA + 8 nt-stores per iter stay in flight one iter).
__global__ __launch_bounds__(256, 2) void vq_main(
    const float* __restrict__ z, const float* __restrict__ w,
    const float* __restrict__ wnorm, const unsigned short* __restrict__ w3,
    float* __restrict__ out,
    float* __restrict__ loss_ws, int* __restrict__ ticket, int* __restrict__ hist)
{
    __shared__ __align__(16) char wl[2 * 24576]; // chunk double-buffer; buf1 also stages z
    __shared__ float snorm[4096];                // wnorm in LDS: keeps loop vmcnt queue clean
    __shared__ int s_widx[64];
    __shared__ int s_flag;

    const int tx    = threadIdx.x;
    const int lane  = tx & 63;
    const int wv    = tx >> 6;
    const int rh    = wv & 1;            // row half: rows rh*32 .. +31
    const int chalf = wv >> 1;           // code half within each chunk
    const int lcol  = lane & 15;         // B col / A row within 16-group
    const int lkq   = lane >> 4;         // k-quarter (8 k's each)
    const int base  = blockIdx.x * 64;   // global rows [base, base+64)
    const int bb    = base >> 12;        // b
    const int hh    = (base & 4095) >> 6;// h   (w coordinate = row-in-block)

    const char* w3b = (const char*)w3;

    // ---- issue DMA of chunk 0 -> buf0 ASAP (drained by the prologue __syncthreads) ----
    {
        const char* s0 = w3b + wv * 6144 + (size_t)lane * 16;
        char* d0 = wl + wv * 6144;
        #pragma unroll
        for (int i = 0; i < 6; ++i)
            __builtin_amdgcn_global_load_lds(
                (const __attribute__((address_space(1))) void*)(s0 + i * 1024),
                (__attribute__((address_space(3))) void*)(d0 + i * 1024), 16, 0, 0);
    }

    // ---- stage z[bb][:][hh][:] into buf1 as float[64][64]; wnorm -> snorm ----
    float (*zS)[64] = (float (*)[64])(wl + 24576);
    #pragma unroll
    for (int j = 0; j < 4; ++j) {
        int f4 = j * 256 + tx;           // 0..1023
        int d  = f4 >> 4, w4i = f4 & 15;
        float4 v = *(const float4*)(z + (((size_t)bb * 64 + d) * 64 + hh) * 64 + w4i * 4);
        *(float4*)&zS[d][w4i * 4] = v;
    }
    #pragma unroll
    for (int j = 0; j < 4; ++j) {
        int c4 = (j * 256 + tx) * 4;
        *(float4*)&snorm[c4] = *(const float4*)(wnorm + c4);
    }
    __syncthreads();                     // z+wnorm staged; chunk-0 DMA also drained

    // ---- A fragments (z limbs) for both 16-row tiles u: rows rh*32 + u*16 + lcol ----
    short8 aH[2][2], aM[2][2], aL[2][2];             // [u][s]
    #pragma unroll
    for (int u = 0; u < 2; ++u)
        #pragma unroll
        for (int s = 0; s < 2; ++s)
            #pragma unroll
            for (int j = 0; j < 8; ++j) {
                float v = zS[s * 32 + lkq * 8 + j][rh * 32 + u * 16 + lcol];
                unsigned short h, m, l;
                split3(v, &h, &m, &l);
                aH[u][s][j] = (short)h; aM[u][s][j] = (short)m; aL[u][s][j] = (short)l;
            }
    __builtin_amdgcn_sched_barrier(0);
    __builtin_amdgcn_s_barrier();        // A built; buf1 free for chunk-1 DMA
    __builtin_amdgcn_sched_barrier(0);

    float best[2][4]; int bidx[2][4];
    #pragma unroll
    for (int u = 0; u < 2; ++u)
        #pragma unroll
        for (int r = 0; r < 4; ++r) { best[u][r] = FLT_MAX; bidx[u][r] = 0; }

    float* enc = out + ENC_OFF;          // 8-B aligned region
    const unsigned sw = ((unsigned)lcol & 7) << 4;    // read-side XOR (matches vq_prep)
    const f32x2 zero2 = {0.f, 0.f};

    // Per chunk: issue DMA(ch+1) + 8 nt zero-fill stores -> vmcnt(14) (retires ONLY the
    // previous iter's 14, drained under compute) -> s_barrier -> MFMA -> s_barrier.
    #pragma unroll 1
    for (int ch = 0; ch < 64; ++ch) {
        const char* cur = wl + (ch & 1) * 24576;
        char*       nxt = wl + (~ch & 1) * 24576;

        // prefetch chunk ch+1 (ch=63: dead reload of chunk 0 into buf0)
        {
            const char* s0 = w3b + (size_t)((ch + 1) & 63) * 24576 + wv * 6144 + (size_t)lane * 16;
            char* d0 = nxt + wv * 6144;
            #pragma unroll
            for (int i = 0; i < 6; ++i)
                __builtin_amdgcn_global_load_lds(
                    (const __attribute__((address_space(1))) void*)(s0 + i * 1024),
                    (__attribute__((address_space(3))) void*)(d0 + i * 1024), 16, 0, 0);
        }
        // zero-fill enc row base+ch, nontemporal (no L2 allocate -> w3 stays L2-resident).
        // Slot map rotated +7 so each 512-B request starts 64-B aligned (row base is
        // +8 mod 64); only the single wrapped request per row still splits lines.
        {
            f32x2* rowp = (f32x2*)(enc + ((size_t)(base + ch) << 12));
            #pragma unroll
            for (int j = 0; j < 8; ++j) {
                int slot = (wv * 512 + j * 64 + lane + 7) & 2047;
                __builtin_nontemporal_store(zero2, rowp + slot);
            }
        }
        __builtin_amdgcn_sched_barrier(0);
        asm volatile("s_waitcnt vmcnt(14)" ::: "memory");   // chunk ch landed in LDS
        __builtin_amdgcn_s_barrier();
        __builtin_amdgcn_sched_barrier(0);

        // ---- compute: dist = ||w||^2 - 2*z.w (row norm constant; argmin unaffected)
        // limb products: hh + (hm+mh) + (mm+hl+lh); dropped ~2^-27 rel.
        {
            const int cbase = ch << 6;
            #pragma unroll
            for (int t = 0; t < 2; ++t) {
                const int clocal = chalf * 32 + t * 16 + lcol;
                const char* rowp = cur + clocal * 384;
                short8 bH0 = *(const short8*)(rowp + ((lkq * 16      ) ^ sw));
                short8 bH1 = *(const short8*)(rowp + ((lkq * 16 +  64) ^ sw));
                short8 bM0 = *(const short8*)(rowp + ((lkq * 16 + 128) ^ sw));
                short8 bM1 = *(const short8*)(rowp + ((lkq * 16 + 192) ^ sw));
                short8 bL0 = *(const short8*)(rowp + ((lkq * 16 + 256) ^ sw));
                short8 bL1 = *(const short8*)(rowp + ((lkq * 16 + 320) ^ sw));
                const float wnv = snorm[cbase + clocal];
                #pragma unroll
                for (int u = 0; u < 2; ++u) {
                    f32x4 c0 = {0.f,0.f,0.f,0.f}, c1 = {0.f,0.f,0.f,0.f}, c2 = {0.f,0.f,0.f,0.f};
                    c0 = MFMA16(aH[u][0], bH0, c0); c0 = MFMA16(aH[u][1], bH1, c0);
                    c1 = MFMA16(aH[u][0], bM0, c1); c1 = MFMA16(aH[u][1], bM1, c1);
                    c1 = MFMA16(aM[u][0], bH0, c1); c1 = MFMA16(aM[u][1], bH1, c1);
                    c2 = MFMA16(aM[u][0], bM0, c2); c2 = MFMA16(aM[u][1], bM1, c2);
                    c2 = MFMA16(aH[u][0], bL0, c2); c2 = MFMA16(aH[u][1], bL1, c2);
                    c2 = MFMA16(aL[u][0], bH0, c2); c2 = MFMA16(aL[u][1], bH1, c2);
                    #pragma unroll
                    for (int r = 0; r < 4; ++r) {
                        float sdot = (c0[r] + c1[r]) + c2[r];
                        float dd = fmaf(-2.f, sdot, wnv);
                        if (dd < best[u][r]) { best[u][r] = dd; bidx[u][r] = cbase + clocal; }
                    }
                }
            }
        }
        __builtin_amdgcn_sched_barrier(0);
        __builtin_amdgcn_s_barrier();    // all waves done reading cur before it's overwritten
    }

    __syncthreads();                     // vmcnt(0): dead DMA + ALL zero-fill stores drained

    // ---- intra-wave argmin butterfly over the 16 code-columns (tie -> lower index) ----
    #pragma unroll
    for (int u = 0; u < 2; ++u)
        #pragma unroll
        for (int mm = 1; mm < 16; mm <<= 1)
            #pragma unroll
            for (int r = 0; r < 4; ++r) {
                float ob = __shfl_xor(best[u][r], mm, 64);
                int   oi = __shfl_xor(bidx[u][r], mm, 64);
                if (ob < best[u][r] || (ob == best[u][r] && oi < bidx[u][r])) {
                    best[u][r] = ob; bidx[u][r] = oi;
                }
            }

    // ---- cross-wave merge of the two code-halves (waves wv and wv^2 share rows) ----
    float2* s_red = (float2*)snorm;      // [64][2]; snorm reads are done (loop ended)
    if (lcol == 0) {
        #pragma unroll
        for (int u = 0; u < 2; ++u)
            #pragma unroll
            for (int r = 0; r < 4; ++r) {
                int row = rh * 32 + u * 16 + lkq * 4 + r;   // m89-verified C layout
                s_red[row * 2 + chalf] = make_float2(best[u][r], __int_as_float(bidx[u][r]));
            }
    }
    __syncthreads();

    if (tx < 64) {
        float2 a = s_red[tx * 2], b2 = s_red[tx * 2 + 1];
        int ai = __float_as_int(a.y), bi2 = __float_as_int(b2.y);
        int bi; float bv;
        if (a.x < b2.x || (a.x == b2.x && ai < bi2)) { bv = a.x; bi = ai; }
        else                                          { bv = b2.x; bi = bi2; }
        (void)bv;
        s_widx[tx] = bi;
        __builtin_nontemporal_store((float)bi, out + IDX_OFF + (size_t)(base + tx));
        atomicAdd(&hist[bi], 1);
        __builtin_nontemporal_store(1.0f, enc + ((size_t)(base + tx) << 12) + bi);
    }
    __syncthreads();

    // ---- z_q (STE rounding) + commitment loss partial; z re-read from global (L2/L3-hot) ----
    {
        const int row = tx & 63;
        const int dg  = tx >> 6;           // 4 waves x 16 d each
        const int wi  = s_widx[row];
        const float* qrow = w + ((size_t)wi << 6);
        float lsum = 0.f;
        #pragma unroll
        for (int dd = 0; dd < 16; ++dd) {
            int d = dg * 16 + dd;
            float qv = qrow[d];
            float zv = z[(((size_t)bb * 64 + d) * 64 + hh) * 64 + row];
            float diff = qv - zv;
            lsum += diff * diff;
            __builtin_nontemporal_store(zv + (qv - zv),
                out + ZQ_OFF + (((size_t)bb * 64 + d) * 64 + hh) * 64 + row);
        }
        #pragma unroll
        for (int off = 32; off > 0; off >>= 1) lsum += __shfl_down(lsum, off, 64);
        if ((tx & 63) == 0) atomicAdd(loss_ws, lsum);
    }

    // ---- fused finalize: last block computes loss scalar + perplexity ----
    __syncthreads();
    if (tx == 0) {
        __threadfence();
        int old = atomicAdd(ticket, 1);
        s_flag = (old == 511) ? 1 : 0;
    }
    __syncthreads();
    if (s_flag) {
        __threadfence();
        float s = 0.f;
        #pragma unroll
        for (int j = 0; j < 16; ++j) {
            int c = tx + j * 256;
            int cnt = atomicAdd(&hist[c], 0);          // device-coherent read
            float p = (float)cnt * (1.f / 32768.f);
            s += p * logf(p + 1e-10f);
        }
        float* fr = snorm;
        fr[tx] = s;
        __syncthreads();
        for (int off = 128; off > 0; off >>= 1) {
            if (tx < off) fr[tx] += fr[tx + off];
            __syncthreads();
        }
        if (tx == 0) {
            out[LOSS_OFF] = BETA * atomicAdd(loss_ws, 0.f) / 2097152.f;
            out[PERP_OFF] = expf(-fr[0]);
        }
    }
}

extern "C" void kernel_launch(void* const* d_in, const int* in_sizes, int n_in,
                              void* d_out, int out_size, void* d_ws, size_t ws_size,
                              hipStream_t stream)
{
    const float* z = (const float*)d_in[0];
    const float* w = (const float*)d_in[1];
    float* out     = (float*)d_out;
    float* loss_ws = (float*)d_ws;
    int*   ticket  = (int*)((char*)d_ws + 4);
    int*   hist    = (int*)((char*)d_ws + 16);
    float* wnorm   = (float*)((char*)d_ws + 16400);
    unsigned short* w3 = (unsigned short*)((char*)d_ws + 32800);   // 1.5 MB swizzled limb table
    (void)ws_size; (void)in_sizes; (void)n_in; (void)out_size;

    hipMemsetAsync(d_ws, 0, 16 + 4096 * sizeof(int), stream);
    vq_wnorm<<<16, 256, 0, stream>>>(w, wnorm);
    vq_prep<<<512, 256, 0, stream>>>(w, w3);
    vq_main<<<512, 256, 0, stream>>>(z, w, wnorm, w3, out, loss_ws, ticket, hist);
}